// Round 2
// baseline (138.900 us; speedup 1.0000x reference)
//
#include <hip/hip_runtime.h>
#include <hip/hip_bf16.h>
#include <math.h>

#define T_FRAMES 65536
#define FSTRIDE  345          // 115 points * 3 coords (float32 elements)

// invert triu(k=1) linear index l -> (a,b) for an N-point set; <=N iterations
__device__ __forceinline__ void triu_ab(int l, int N, int& a, int& b) {
  int a0 = 0, rem = l, row = N - 1;
  while (rem >= row) { rem -= row; ++a0; --row; }
  a = a0; b = a0 + 1 + rem;
}

// ---- phase 1: per-frame packed {nonzero-count (7b) | keep-bit (bit7)} ------
// One wave (64 lanes) per frame; lanes 0..62 read the 63 floats of each hand.
__global__ __launch_bounds__(256) void phase1(const float* __restrict__ x,
                                              uchar2* __restrict__ keepF) {
  const int wave = threadIdx.x >> 6;
  const int lane = threadIdx.x & 63;
  const int f = (blockIdx.x << 2) + wave;
  const float* xf = x + (size_t)f * FSTRIDE;
  float vl = 0.f, vr = 0.f; int cl = 0, cr = 0;
  if (lane < 63) {
    float a = xf[120 + lane]; if (isnan(a)) a = 0.f;  // left hand: pts 40..60
    float b = xf[282 + lane]; if (isnan(b)) b = 0.f;  // right hand: pts 94..114
    vl = a; vr = b; cl = (a != 0.f); cr = (b != 0.f);
  }
  for (int off = 32; off > 0; off >>= 1) {
    vl += __shfl_down(vl, off, 64);
    vr += __shfl_down(vr, off, 64);
    cl += __shfl_down(cl, off, 64);
    cr += __shfl_down(cr, off, 64);
  }
  if (lane == 0) {
    uchar2 k;
    k.x = (unsigned char)(cl | ((vl != 0.f) ? 0x80 : 0));
    k.y = (unsigned char)(cr | ((vr != 0.f) ? 0x80 : 0));
    keepF[f] = k;
  }
}

// ---- phase 2: cond + first 101 entries of the stable keep-first order ------
__global__ __launch_bounds__(1024) void phase2(const uchar2* __restrict__ keepF,
                                               int* __restrict__ condP,
                                               int* __restrict__ order) {
  __shared__ int sc[1024];
  __shared__ int sBase, sCond;
  const int tid = threadIdx.x;

  // total nonzero-element counts for each hand slab
  int cl = 0, cr = 0;
  for (int i = tid; i < T_FRAMES; i += 1024) {
    uchar2 v = keepF[i]; cl += v.x & 0x7F; cr += v.y & 0x7F;
  }
  sc[tid] = cl; __syncthreads();
  for (int off = 512; off > 0; off >>= 1) { if (tid < off) sc[tid] += sc[tid + off]; __syncthreads(); }
  const int totL = sc[0]; __syncthreads();
  sc[tid] = cr; __syncthreads();
  for (int off = 512; off > 0; off >>= 1) { if (tid < off) sc[tid] += sc[tid + off]; __syncthreads(); }
  const int totR = sc[0]; __syncthreads();
  if (tid == 0) { sCond = (totL > totR) ? 1 : 0; condP[0] = sCond; sBase = 0; }
  __syncthreads();
  const int cond = sCond;

  // stable partition: keep frames (ascending) then non-keep (ascending); need first 101
  for (int pass = 0; pass < 2; ++pass) {
    bool done = false;
    for (int base = 0; base < T_FRAMES; base += 1024) {
      const int f = base + tid;
      uchar2 k = keepF[f];
      int flag = (cond ? (int)k.x : (int)k.y) >> 7;
      if (pass == 1) flag ^= 1;
      sc[tid] = flag; __syncthreads();
      for (int off = 1; off < 1024; off <<= 1) {           // Hillis-Steele inclusive scan
        int v = (tid >= off) ? sc[tid - off] : 0;
        __syncthreads();
        sc[tid] += v;
        __syncthreads();
      }
      const int incl = sc[tid];
      const int tot  = sc[1023];
      const int basec = sBase;
      if (flag && (basec + incl - 1) < 101) order[basec + incl - 1] = f;
      __syncthreads();
      if (tid == 0) sBase = basec + tot;
      __syncthreads();
      if (sBase >= 101) { done = true; break; }
    }
    if (done) break;
  }
}

// ---- phase 3: build the 100 x 1196 output ----------------------------------
__global__ __launch_bounds__(256) void phase3(const float* __restrict__ x,
                                              const int* __restrict__ condP,
                                              const int* __restrict__ order,
                                              float* __restrict__ out) {
  __shared__ float A[258], B[258];   // xfeat (86 pts x 3) for frames order[row], order[row+1]
  const int row  = blockIdx.x;
  const int cond = condP[0];
  const int f = order[row], g = order[row + 1];
  const float* xf = x + (size_t)f * FSTRIDE;
  const float* xg = x + (size_t)g * FSTRIDE;

  for (int idx = threadIdx.x; idx < 258; idx += blockDim.x) {
    const int p = idx / 3, c = idx - p * 3;
    // xfeat point -> source point in x: hand(21) | pose(25) | lip(40)
    const int s = (p < 21) ? (cond ? 40 + p : 94 + p) : ((p < 46) ? p + 40 : p - 46);
    float va = xf[s * 3 + c]; if (isnan(va)) va = 0.f;
    float vb = xg[s * 3 + c]; if (isnan(vb)) vb = 0.f;
    if (cond && c == 0) { va = -va; vb = -vb; }   // xc negation applies to all 86 points
    A[idx] = va; B[idx] = vb;
  }
  __syncthreads();

  float* o = out + (size_t)row * 1196;
  for (int j = threadIdx.x; j < 1196; j += blockDim.x) {
    float v;
    if (j < 306) {                       // positional: xfeat (153) then dxyz (153)
      int jj = j; bool diff = false;
      if (jj >= 153) { diff = true; jj -= 153; }
      int p, c;
      if (jj < 63)       { p = jj / 3;             c = jj - p * 3; }
      else if (jj < 113) { int t = jj - 63;  p = 21 + (t >> 1); c = t & 1; }
      else               { int t = jj - 113; p = 46 + (t >> 1); c = t & 1; }
      v = A[p * 3 + c];
      if (diff) v -= B[p * 3 + c];
    } else if (j < 516) {                // hdist: 21 pts, 3D, 210 pairs
      int a, b; triu_ab(j - 306, 21, a, b);
      const float dx = A[a*3]   - A[b*3];
      const float dy = A[a*3+1] - A[b*3+1];
      const float dz = A[a*3+2] - A[b*3+2];
      v = sqrtf(dx*dx + dy*dy + dz*dz);
    } else if (j < 816) {                // pdist: pose 25 pts, 2D, 300 pairs
      int a, b; triu_ab(j - 516, 25, a, b);
      a += 21; b += 21;
      const float dx = A[a*3] - A[b*3], dy = A[a*3+1] - A[b*3+1];
      v = sqrtf(dx*dx + dy*dy);
    } else if (j < 1006) {               // oldist: lip pts 46..65, 2D, 190 pairs
      int a, b; triu_ab(j - 816, 20, a, b);
      a += 46; b += 46;
      const float dx = A[a*3] - A[b*3], dy = A[a*3+1] - A[b*3+1];
      v = sqrtf(dx*dx + dy*dy);
    } else {                             // ildist: lip pts 66..85, 2D, 190 pairs
      int a, b; triu_ab(j - 1006, 20, a, b);
      a += 66; b += 66;
      const float dx = A[a*3] - A[b*3], dy = A[a*3+1] - A[b*3+1];
      v = sqrtf(dx*dx + dy*dy);
    }
    o[j] = v;
  }
}

extern "C" void kernel_launch(void* const* d_in, const int* in_sizes, int n_in,
                              void* d_out, int out_size, void* d_ws, size_t ws_size,
                              hipStream_t stream) {
  const float* x = (const float*)d_in[0];
  float* out = (float*)d_out;
  char* ws = (char*)d_ws;
  // ws layout (everything read is written first each launch; 0xAA poison harmless):
  //   [0,4)            int    cond
  //   [16,432)         int    order[104]
  //   [512,131584)     uchar2 keepF[65536]   (128 KB)  -> total ~132 KB
  int*    condP = (int*)ws;
  int*    order = (int*)(ws + 16);
  uchar2* keepF = (uchar2*)(ws + 512);

  phase1<<<T_FRAMES / 4, 256, 0, stream>>>(x, keepF);
  phase2<<<1, 1024, 0, stream>>>(keepF, condP, order);
  phase3<<<100, 256, 0, stream>>>(x, condP, order, out);
}

// Round 3
// 136.387 us; speedup vs baseline: 1.0184x; 1.0184x over previous
//
#include <hip/hip_runtime.h>
#include <hip/hip_bf16.h>
#include <math.h>

#define T_FRAMES 65536
#define FSTRIDE  345          // 115 points * 3 coords (float32 elements)

// invert triu(k=1) linear index l -> (a,b) for an N-point set; <=N iterations
__device__ __forceinline__ void triu_ab(int l, int N, int& a, int& b) {
  int a0 = 0, rem = l, row = N - 1;
  while (rem >= row) { rem -= row; ++a0; --row; }
  a = a0; b = a0 + 1 + rem;
}

// ---- phase 1: per-frame packed {nonzero-count (7b) | keep-bit (bit7)} ------
// One wave (64 lanes) per frame; lanes 0..62 read the 63 floats of each hand.
__global__ __launch_bounds__(256) void phase1(const float* __restrict__ x,
                                              uchar2* __restrict__ keepF) {
  const int wave = threadIdx.x >> 6;
  const int lane = threadIdx.x & 63;
  const int f = (blockIdx.x << 2) + wave;
  const float* xf = x + (size_t)f * FSTRIDE;
  float vl = 0.f, vr = 0.f; int cl = 0, cr = 0;
  if (lane < 63) {
    float a = xf[120 + lane]; if (isnan(a)) a = 0.f;  // left hand: pts 40..60
    float b = xf[282 + lane]; if (isnan(b)) b = 0.f;  // right hand: pts 94..114
    vl = a; vr = b; cl = (a != 0.f); cr = (b != 0.f);
  }
  for (int off = 32; off > 0; off >>= 1) {
    vl += __shfl_down(vl, off, 64);
    vr += __shfl_down(vr, off, 64);
    cl += __shfl_down(cl, off, 64);
    cr += __shfl_down(cr, off, 64);
  }
  if (lane == 0) {
    uchar2 k;
    k.x = (unsigned char)(cl | ((vl != 0.f) ? 0x80 : 0));
    k.y = (unsigned char)(cr | ((vr != 0.f) ? 0x80 : 0));
    keepF[f] = k;
  }
}

// ---- phase 2: cond + first 101 entries of the stable keep-first order ------
// Ballot-based compaction: 1024 threads, one 1024-frame tile per iteration,
// two barriers per tile, fully parallel position computation via popcount.
__global__ __launch_bounds__(1024) void phase2(const uchar2* __restrict__ keepF,
                                               int* __restrict__ condP,
                                               int* __restrict__ order) {
  const int tid  = threadIdx.x;
  const int lane = tid & 63;
  const int wave = tid >> 6;
  __shared__ int sL[16], sR[16];
  __shared__ unsigned long long sM[16];
  __shared__ int sBase, sCond;

  // ---- totals: sum 7-bit counts, vectorized as uint4 (16 bytes = 8 frames) ----
  const uint4* kp = (const uint4*)keepF;          // 8192 uint4 total
  int cl = 0, cr = 0;
  for (int i = tid; i < (T_FRAMES * 2 / 16); i += 1024) {
    uint4 v = kp[i];
    // byte layout per uint: [f.x, f.y, f+1.x, f+1.y] -> left = bytes 0,2; right = bytes 1,3
    unsigned t;
    t = v.x & 0x7F7F7F7Fu; cl += (t & 0xFF) + ((t >> 16) & 0xFF); cr += ((t >> 8) & 0xFF) + ((t >> 24) & 0xFF);
    t = v.y & 0x7F7F7F7Fu; cl += (t & 0xFF) + ((t >> 16) & 0xFF); cr += ((t >> 8) & 0xFF) + ((t >> 24) & 0xFF);
    t = v.z & 0x7F7F7F7Fu; cl += (t & 0xFF) + ((t >> 16) & 0xFF); cr += ((t >> 8) & 0xFF) + ((t >> 24) & 0xFF);
    t = v.w & 0x7F7F7F7Fu; cl += (t & 0xFF) + ((t >> 16) & 0xFF); cr += ((t >> 8) & 0xFF) + ((t >> 24) & 0xFF);
  }
  for (int off = 32; off > 0; off >>= 1) {
    cl += __shfl_down(cl, off, 64);
    cr += __shfl_down(cr, off, 64);
  }
  if (lane == 0) { sL[wave] = cl; sR[wave] = cr; }
  __syncthreads();
  if (tid == 0) {
    int L = 0, R = 0;
    for (int i = 0; i < 16; ++i) { L += sL[i]; R += sR[i]; }
    sCond = (L > R) ? 1 : 0;
    condP[0] = sCond;
    sBase = 0;
  }
  __syncthreads();
  const int cond = sCond;

  // ---- stable partition: keep-first (pass 0), then non-keep (pass 1) ----
  for (int pass = 0; pass < 2; ++pass) {
    for (int base = 0; base < T_FRAMES; base += 1024) {
      if (sBase >= 101) break;                   // uniform; sBase stable since last barrier
      uchar2 k = keepF[base + tid];
      int flag = ((cond ? (int)k.x : (int)k.y) >> 7) & 1;
      if (pass) flag ^= 1;
      unsigned long long m = __ballot(flag);
      if (lane == 0) sM[wave] = m;
      __syncthreads();
      int pos = sBase;
      for (int w = 0; w < wave; ++w) pos += __popcll(sM[w]);
      pos += (int)__popcll(m & ((1ull << lane) - 1ull));
      if (flag && pos < 101) order[pos] = base + tid;
      __syncthreads();
      if (tid == 0) {
        int tot = 0;
        for (int w = 0; w < 16; ++w) tot += (int)__popcll(sM[w]);
        sBase += tot;
      }
      __syncthreads();
    }
  }
}

// ---- phase 3: build the 100 x 1196 output ----------------------------------
__global__ __launch_bounds__(256) void phase3(const float* __restrict__ x,
                                              const int* __restrict__ condP,
                                              const int* __restrict__ order,
                                              float* __restrict__ out) {
  __shared__ float A[258], B[258];   // xfeat (86 pts x 3) for frames order[row], order[row+1]
  const int row  = blockIdx.x;
  const int cond = condP[0];
  const int f = order[row], g = order[row + 1];
  const float* xf = x + (size_t)f * FSTRIDE;
  const float* xg = x + (size_t)g * FSTRIDE;

  for (int idx = threadIdx.x; idx < 258; idx += blockDim.x) {
    const int p = idx / 3, c = idx - p * 3;
    // xfeat point -> source point in x: hand(21) | pose(25) | lip(40)
    const int s = (p < 21) ? (cond ? 40 + p : 94 + p) : ((p < 46) ? p + 40 : p - 46);
    float va = xf[s * 3 + c]; if (isnan(va)) va = 0.f;
    float vb = xg[s * 3 + c]; if (isnan(vb)) vb = 0.f;
    if (cond && c == 0) { va = -va; vb = -vb; }   // xc negation applies to all 86 points
    A[idx] = va; B[idx] = vb;
  }
  __syncthreads();

  float* o = out + (size_t)row * 1196;
  for (int j = threadIdx.x; j < 1196; j += blockDim.x) {
    float v;
    if (j < 306) {                       // positional: xfeat (153) then dxyz (153)
      int jj = j; bool diff = false;
      if (jj >= 153) { diff = true; jj -= 153; }
      int p, c;
      if (jj < 63)       { p = jj / 3;             c = jj - p * 3; }
      else if (jj < 113) { int t = jj - 63;  p = 21 + (t >> 1); c = t & 1; }
      else               { int t = jj - 113; p = 46 + (t >> 1); c = t & 1; }
      v = A[p * 3 + c];
      if (diff) v -= B[p * 3 + c];
    } else if (j < 516) {                // hdist: 21 pts, 3D, 210 pairs
      int a, b; triu_ab(j - 306, 21, a, b);
      const float dx = A[a*3]   - A[b*3];
      const float dy = A[a*3+1] - A[b*3+1];
      const float dz = A[a*3+2] - A[b*3+2];
      v = sqrtf(dx*dx + dy*dy + dz*dz);
    } else if (j < 816) {                // pdist: pose 25 pts, 2D, 300 pairs
      int a, b; triu_ab(j - 516, 25, a, b);
      a += 21; b += 21;
      const float dx = A[a*3] - A[b*3], dy = A[a*3+1] - A[b*3+1];
      v = sqrtf(dx*dx + dy*dy);
    } else if (j < 1006) {               // oldist: lip pts 46..65, 2D, 190 pairs
      int a, b; triu_ab(j - 816, 20, a, b);
      a += 46; b += 46;
      const float dx = A[a*3] - A[b*3], dy = A[a*3+1] - A[b*3+1];
      v = sqrtf(dx*dx + dy*dy);
    } else {                             // ildist: lip pts 66..85, 2D, 190 pairs
      int a, b; triu_ab(j - 1006, 20, a, b);
      a += 66; b += 66;
      const float dx = A[a*3] - A[b*3], dy = A[a*3+1] - A[b*3+1];
      v = sqrtf(dx*dx + dy*dy);
    }
    o[j] = v;
  }
}

extern "C" void kernel_launch(void* const* d_in, const int* in_sizes, int n_in,
                              void* d_out, int out_size, void* d_ws, size_t ws_size,
                              hipStream_t stream) {
  const float* x = (const float*)d_in[0];
  float* out = (float*)d_out;
  char* ws = (char*)d_ws;
  // ws layout (everything read is written first each launch; 0xAA poison harmless):
  //   [0,4)            int    cond
  //   [16,432)         int    order[104]
  //   [512,131584)     uchar2 keepF[65536]   (128 KB)  -> total ~132 KB
  int*    condP = (int*)ws;
  int*    order = (int*)(ws + 16);
  uchar2* keepF = (uchar2*)(ws + 512);

  phase1<<<T_FRAMES / 4, 256, 0, stream>>>(x, keepF);
  phase2<<<1, 1024, 0, stream>>>(keepF, condP, order);
  phase3<<<100, 256, 0, stream>>>(x, condP, order, out);
}